// Round 1
// baseline (374.267 us; speedup 1.0000x reference)
//
#include <hip/hip_runtime.h>

typedef unsigned short u16;
typedef u16 u16x4 __attribute__((ext_vector_type(4)));
typedef u16 u16x8 __attribute__((ext_vector_type(8)));
typedef __bf16 bf16x8 __attribute__((ext_vector_type(8)));
typedef float f32x4 __attribute__((ext_vector_type(4)));

static __device__ __forceinline__ u16 f2bf(float f) {
  unsigned u = __builtin_bit_cast(unsigned, f);
  u += 0x7fffu + ((u >> 16) & 1u);   // RNE; inputs are finite, no NaN handling needed
  return (u16)(u >> 16);
}
static __device__ __forceinline__ float bf2f(u16 h) {
  return __builtin_bit_cast(float, ((unsigned)h) << 16);
}

// async global->LDS, 16B per lane. LDS dest = wave-uniform base + lane*16.
static __device__ __forceinline__ void gload_lds16(const u16* g, u16* l) {
  u16* gn = const_cast<u16*>(g);
  __builtin_amdgcn_global_load_lds(
      (__attribute__((address_space(1))) unsigned int*)gn,
      (__attribute__((address_space(3))) unsigned int*)l,
      16, 0, 0);
}

__global__ __launch_bounds__(256)
void cvt_f32_bf16(const float* __restrict__ in, u16* __restrict__ out) {
  const int i = blockIdx.x * 256 + threadIdx.x;
  float4 f = ((const float4*)in)[i];
  u16x4 o = { f2bf(f.x), f2bf(f.y), f2bf(f.z), f2bf(f.w) };
  ((u16x4*)out)[i] = o;
}

// C[m][n] = sum_k A[m][k] * B[n][k]   (both row-major with k contiguous)
// MODE 0: bf16 out, +bias, row-major ldc        (Q,K projections)
// MODE 1: bf16 out, +bias, transposed V^T[b][n][s], s=m&2047, b=m>>11
// MODE 2: bf16 out, *alpha, row-major ldc        (logits)
// MODE 3: fp32 out, row-major ldc                (attn @ V^T)
template<int MODE>
__global__ __launch_bounds__(256)
void gemm_bt(const u16* __restrict__ Ain, const u16* __restrict__ Bin,
             void* __restrict__ Cv, const float* __restrict__ bias,
             int lda, int ldb, int ldc, int K, float alpha,
             unsigned long long sA, unsigned long long sB, unsigned long long sC)
{
  constexpr int BM = 128, BN = 128, BK = 32;
  __shared__ alignas(16) u16 As[BM * BK];
  __shared__ alignas(16) u16 Bs[BN * BK];

  const u16* A = Ain + blockIdx.z * sA;
  const u16* B = Bin + blockIdx.z * sB;

  const int tid  = threadIdx.x;
  const int wave = tid >> 6;
  const int lane = tid & 63;
  const int quad = lane >> 4;
  const int l16  = lane & 15;
  const int wr   = wave >> 1;     // 2x2 wave grid, each wave does 64x64
  const int wc   = wave & 1;

  const int m0 = blockIdx.y * BM;
  const int n0 = blockIdx.x * BN;

  // staging: each wave loads 32 rows of A-tile and B-tile (2 x 16-row instrs each)
  const u16* Ag = A + (size_t)(m0 + wave * 32 + (lane >> 2)) * lda + (lane & 3) * 8;
  const u16* Bg = B + (size_t)(n0 + wave * 32 + (lane >> 2)) * ldb + (lane & 3) * 8;
  u16* As0 = &As[(wave * 32 + 0)  * BK];
  u16* As1 = &As[(wave * 32 + 16) * BK];
  u16* Bs0 = &Bs[(wave * 32 + 0)  * BK];
  u16* Bs1 = &Bs[(wave * 32 + 16) * BK];

  f32x4 acc[4][4];
  #pragma unroll
  for (int i = 0; i < 4; ++i)
    #pragma unroll
    for (int j = 0; j < 4; ++j)
      acc[i][j] = (f32x4){0.f, 0.f, 0.f, 0.f};

  for (int k0 = 0; k0 < K; k0 += BK) {
    gload_lds16(Ag + k0,                    As0);
    gload_lds16(Ag + (size_t)16 * lda + k0, As1);
    gload_lds16(Bg + k0,                    Bs0);
    gload_lds16(Bg + (size_t)16 * ldb + k0, Bs1);
    __syncthreads();   // drains vmcnt -> staged data visible to all waves

    bf16x8 af[4], bfr[4];
    #pragma unroll
    for (int mi = 0; mi < 4; ++mi)
      af[mi] = *(const bf16x8*)&As[(wr * 64 + mi * 16 + l16) * BK + quad * 8];
    #pragma unroll
    for (int ni = 0; ni < 4; ++ni)
      bfr[ni] = *(const bf16x8*)&Bs[(wc * 64 + ni * 16 + l16) * BK + quad * 8];

    #pragma unroll
    for (int mi = 0; mi < 4; ++mi)
      #pragma unroll
      for (int ni = 0; ni < 4; ++ni)
        acc[mi][ni] = __builtin_amdgcn_mfma_f32_16x16x32_bf16(af[mi], bfr[ni], acc[mi][ni], 0, 0, 0);

    __syncthreads();
  }

  // C[mbase + mi*16 + r][nbase + ni*16] per lane (row = quad*4+r, col = l16)
  const int mbase = m0 + wr * 64 + quad * 4;
  const int nbase = n0 + wc * 64 + l16;

  if constexpr (MODE == 0) {
    u16* Cb = (u16*)Cv;
    #pragma unroll
    for (int ni = 0; ni < 4; ++ni) {
      const int col = nbase + ni * 16;
      const float bv = bias[col];
      #pragma unroll
      for (int mi = 0; mi < 4; ++mi) {
        const size_t base = (size_t)(mbase + mi * 16) * ldc + col;
        #pragma unroll
        for (int r = 0; r < 4; ++r)
          Cb[base + (size_t)r * ldc] = f2bf(acc[mi][ni][r] + bv);
      }
    }
  } else if constexpr (MODE == 1) {
    u16* Cb = (u16*)Cv;
    #pragma unroll
    for (int ni = 0; ni < 4; ++ni) {
      const int col = nbase + ni * 16;
      const float bv = bias[col];
      #pragma unroll
      for (int mi = 0; mi < 4; ++mi) {
        const int row = mbase + mi * 16;
        u16x4 o;
        #pragma unroll
        for (int r = 0; r < 4; ++r) o[r] = f2bf(acc[mi][ni][r] + bv);
        const size_t idx = ((size_t)((row >> 11) * 1024 + col)) * 2048 + (row & 2047);
        *(u16x4*)&Cb[idx] = o;   // 4 consecutive s -> 8B store
      }
    }
  } else if constexpr (MODE == 2) {
    u16* Cb = (u16*)Cv + blockIdx.z * sC;
    #pragma unroll
    for (int ni = 0; ni < 4; ++ni) {
      const int col = nbase + ni * 16;
      #pragma unroll
      for (int mi = 0; mi < 4; ++mi) {
        const size_t base = (size_t)(mbase + mi * 16) * ldc + col;
        #pragma unroll
        for (int r = 0; r < 4; ++r)
          Cb[base + (size_t)r * ldc] = f2bf(acc[mi][ni][r] * alpha);
      }
    }
  } else {
    float* Cf = (float*)Cv + blockIdx.z * sC;
    #pragma unroll
    for (int ni = 0; ni < 4; ++ni) {
      const int col = nbase + ni * 16;
      #pragma unroll
      for (int mi = 0; mi < 4; ++mi) {
        const size_t base = (size_t)(mbase + mi * 16) * ldc + col;
        #pragma unroll
        for (int r = 0; r < 4; ++r)
          Cf[base + (size_t)r * ldc] = acc[mi][ni][r];
      }
    }
  }
}

// one block per row of 2048; reads bf16 logits, writes fp32 attn to d_out and
// bf16 attn in-place over the logits buffer (input to the PV gemm).
__global__ __launch_bounds__(256)
void softmax_rows(u16* __restrict__ logits, float* __restrict__ attn) {
  const int row = blockIdx.x;
  const int tid = threadIdx.x;
  u16*  lp = logits + (size_t)row * 2048 + tid * 8;
  float* ap = attn  + (size_t)row * 2048 + tid * 8;

  u16x8 raw = *(const u16x8*)lp;
  float v[8];
  #pragma unroll
  for (int j = 0; j < 8; ++j) v[j] = bf2f(raw[j]);

  float mx = v[0];
  #pragma unroll
  for (int j = 1; j < 8; ++j) mx = fmaxf(mx, v[j]);
  #pragma unroll
  for (int o = 32; o > 0; o >>= 1) mx = fmaxf(mx, __shfl_xor(mx, o, 64));

  __shared__ float smax[4], ssum[4];
  const int wv = tid >> 6, ln = tid & 63;
  if (ln == 0) smax[wv] = mx;
  __syncthreads();
  mx = fmaxf(fmaxf(smax[0], smax[1]), fmaxf(smax[2], smax[3]));

  float s = 0.f;
  #pragma unroll
  for (int j = 0; j < 8; ++j) { v[j] = __expf(v[j] - mx); s += v[j]; }
  #pragma unroll
  for (int o = 32; o > 0; o >>= 1) s += __shfl_xor(s, o, 64);
  if (ln == 0) ssum[wv] = s;
  __syncthreads();
  s = (ssum[0] + ssum[1]) + (ssum[2] + ssum[3]);
  const float inv = 1.f / s;

  u16x8 ob;
  #pragma unroll
  for (int j = 0; j < 8; ++j) { v[j] *= inv; ob[j] = f2bf(v[j]); }
  float4* apv = (float4*)ap;
  apv[0] = make_float4(v[0], v[1], v[2], v[3]);
  apv[1] = make_float4(v[4], v[5], v[6], v[7]);
  *(u16x8*)lp = ob;
}

extern "C" void kernel_launch(void* const* d_in, const int* in_sizes, int n_in,
                              void* d_out, int out_size, void* d_ws, size_t ws_size,
                              hipStream_t stream) {
  (void)in_sizes; (void)n_in; (void)out_size; (void)ws_size;
  const float* x    = (const float*)d_in[0];
  const float* wq_w = (const float*)d_in[1];
  const float* wq_b = (const float*)d_in[2];
  const float* wk_w = (const float*)d_in[3];
  const float* wk_b = (const float*)d_in[4];
  const float* wv_w = (const float*)d_in[5];
  const float* wv_b = (const float*)d_in[6];

  float* attn = (float*)d_out;                 // [4,2048,2048] fp32
  float* outp = attn + 16777216ULL;            // [4,2048,1024] fp32

  // ws layout (u16 elems): x_bf | wq | wk | wv | Q | K | V^T | logits/attn_bf16
  u16* xb  = (u16*)d_ws;
  u16* wqb = xb  + 8388608ULL;
  u16* wkb = wqb + 1048576ULL;
  u16* wvb = wkb + 1048576ULL;
  u16* Qb  = wvb + 1048576ULL;   // [8192][1024]
  u16* Kb  = Qb  + 8388608ULL;   // [8192][1024]
  u16* Vt  = Kb  + 8388608ULL;   // [4][1024][2048]
  u16* Lg  = Vt  + 8388608ULL;   // [4][2048][2048]

  cvt_f32_bf16<<<8192, 256, 0, stream>>>(x,    xb);
  cvt_f32_bf16<<<1024, 256, 0, stream>>>(wq_w, wqb);
  cvt_f32_bf16<<<1024, 256, 0, stream>>>(wk_w, wkb);
  cvt_f32_bf16<<<1024, 256, 0, stream>>>(wv_w, wvb);

  // projections: M=8192, N=1024, K=1024
  gemm_bt<0><<<dim3(8, 64, 1), 256, 0, stream>>>(xb, wqb, Qb, wq_b, 1024, 1024, 1024, 1024, 1.f, 0, 0, 0);
  gemm_bt<0><<<dim3(8, 64, 1), 256, 0, stream>>>(xb, wkb, Kb, wk_b, 1024, 1024, 1024, 1024, 1.f, 0, 0, 0);
  gemm_bt<1><<<dim3(8, 64, 1), 256, 0, stream>>>(xb, wvb, Vt, wv_b, 1024, 1024, 0,    1024, 1.f, 0, 0, 0);

  // logits = Q K^T / 32 per batch: M=N=2048, K=1024
  gemm_bt<2><<<dim3(16, 16, 4), 256, 0, stream>>>(Qb, Kb, Lg, nullptr, 1024, 1024, 2048, 1024, 0.03125f,
                                                  2097152ULL, 2097152ULL, 4194304ULL);
  softmax_rows<<<8192, 256, 0, stream>>>(Lg, attn);

  // out = attn V: M=2048, N=1024, K=2048 per batch
  gemm_bt<3><<<dim3(8, 16, 4), 256, 0, stream>>>(Lg, Vt, outp, nullptr, 2048, 2048, 1024, 2048, 1.f,
                                                 4194304ULL, 2097152ULL, 2097152ULL);
}

// Round 2
// 309.112 us; speedup vs baseline: 1.2108x; 1.2108x over previous
//
#include <hip/hip_runtime.h>

typedef unsigned short u16;
typedef u16 u16x4 __attribute__((ext_vector_type(4)));
typedef u16 u16x8 __attribute__((ext_vector_type(8)));
typedef __bf16 bf16x8 __attribute__((ext_vector_type(8)));
typedef float f32x4 __attribute__((ext_vector_type(4)));

static __device__ __forceinline__ u16 f2bf(float f) {
  unsigned u = __builtin_bit_cast(unsigned, f);
  u += 0x7fffu + ((u >> 16) & 1u);   // RNE; finite inputs
  return (u16)(u >> 16);
}
static __device__ __forceinline__ float bf2f(u16 h) {
  return __builtin_bit_cast(float, ((unsigned)h) << 16);
}

// async global->LDS, 16B/lane. LDS dest = wave-uniform base + lane*16.
static __device__ __forceinline__ void gload_lds16(const u16* g, u16* l) {
  u16* gn = const_cast<u16*>(g);
  __builtin_amdgcn_global_load_lds(
      (__attribute__((address_space(1))) unsigned int*)gn,
      (__attribute__((address_space(3))) unsigned int*)l,
      16, 0, 0);
}

__global__ __launch_bounds__(256)
void cvt_f32_bf16(const float* __restrict__ in, u16* __restrict__ out) {
  const int i = blockIdx.x * 256 + threadIdx.x;
  float4 f = ((const float4*)in)[i];
  u16x4 o = { f2bf(f.x), f2bf(f.y), f2bf(f.z), f2bf(f.w) };
  ((u16x4*)out)[i] = o;
}

// converts 3 weight matrices [1024x1024] into one contiguous bf16 buffer
__global__ __launch_bounds__(256)
void cvt_w3(const float* __restrict__ a, const float* __restrict__ b,
            const float* __restrict__ c, u16* __restrict__ out) {
  const int blk = blockIdx.x;       // 0..3071
  const int w = blk >> 10;
  const float* src = (w == 0) ? a : (w == 1) ? b : c;
  const int i = (blk & 1023) * 256 + threadIdx.x;
  float4 f = ((const float4*)src)[i];
  u16x4 o = { f2bf(f.x), f2bf(f.y), f2bf(f.z), f2bf(f.w) };
  ((u16x4*)(out + (size_t)w * 1048576ULL))[i] = o;
}

// C[m][n] = sum_k A[m][k]*B[n][k], both k-contiguous. BM=BN=128, BK=64.
// LDS XOR swizzle: LDS(row, chunk) holds global chunk (chunk ^ (row&7)),
// realized by permuting the per-lane GLOBAL source address in the staging
// loads (global_load_lds LDS dest is fixed at base+lane*16).
// MODE 0: fused QKV epilogue. Cv = Q base; K at +8M elems; V^T at +16M.
//         col group g = n0>>10 selects {Q,K,V}; V stored transposed [b][d][s].
// MODE 2: bf16 out, *alpha, row-major ldc, z-strided   (logits)
// MODE 3: fp32 out, row-major ldc, z-strided           (attn @ V^T)
template<int MODE>
__global__ __launch_bounds__(256)
void gemm_bt(const u16* __restrict__ Ain, const u16* __restrict__ Bin,
             void* __restrict__ Cv,
             const float* __restrict__ b0, const float* __restrict__ b1,
             const float* __restrict__ b2,
             int lda, int ldb, int ldc, int K, float alpha,
             unsigned long long sA, unsigned long long sB, unsigned long long sC,
             int nbx, int nby)
{
  constexpr int BM = 128, BN = 128, BK = 64;
  __shared__ alignas(16) u16 As[BM * BK];
  __shared__ alignas(16) u16 Bs[BN * BK];

  // XCD-chunk (assume round-robin linear-id -> XCD) + group-m swizzle
  const int nbxy = nbx * nby;
  const int bid  = blockIdx.x;
  const int flat = (bid & 7) * ((int)gridDim.x >> 3) + (bid >> 3);
  const int z    = flat / nbxy;
  const int rr   = flat - z * nbxy;
  const int width = nbx << 3;
  const int gid  = rr / width;
  const int rw   = rr - gid * width;
  const int by   = (gid << 3) + (rw & 7);   // m-tile
  const int bx   = rw >> 3;                 // n-tile

  const u16* A = Ain + z * sA;
  const u16* B = Bin + z * sB;

  const int tid  = threadIdx.x;
  const int wave = tid >> 6;
  const int lane = tid & 63;
  const int quad = lane >> 4;
  const int l16  = lane & 15;
  const int wr   = wave >> 1;     // 2x2 wave grid, 64x64 per wave
  const int wc   = wave & 1;

  const int m0 = by * BM;
  const int n0 = bx * BN;

  // staging: per instruction 64 lanes cover 8 rows x 8 chunks(16B) of [*][64]
  const int lr = lane >> 3;                 // row within 8-row group
  const int sc = ((lane & 7) ^ lr) * 8;     // swizzled global chunk offset
  const u16* Ag = A + (size_t)(m0 + wave * 32 + lr) * lda + sc;
  const u16* Bg = B + (size_t)(n0 + wave * 32 + lr) * ldb + sc;
  u16* Asb = &As[(wave * 32) * BK];
  u16* Bsb = &Bs[(wave * 32) * BK];

  f32x4 acc[4][4];
  #pragma unroll
  for (int i = 0; i < 4; ++i)
    #pragma unroll
    for (int j = 0; j < 4; ++j)
      acc[i][j] = (f32x4){0.f, 0.f, 0.f, 0.f};

  for (int k0 = 0; k0 < K; k0 += BK) {
    gload_lds16(Ag + k0,                    Asb);
    gload_lds16(Ag + (size_t) 8 * lda + k0, Asb +  8 * BK);
    gload_lds16(Ag + (size_t)16 * lda + k0, Asb + 16 * BK);
    gload_lds16(Ag + (size_t)24 * lda + k0, Asb + 24 * BK);
    gload_lds16(Bg + k0,                    Bsb);
    gload_lds16(Bg + (size_t) 8 * ldb + k0, Bsb +  8 * BK);
    gload_lds16(Bg + (size_t)16 * ldb + k0, Bsb + 16 * BK);
    gload_lds16(Bg + (size_t)24 * ldb + k0, Bsb + 24 * BK);
    __syncthreads();

    #pragma unroll
    for (int ks = 0; ks < 2; ++ks) {
      bf16x8 af[4], bfr[4];
      #pragma unroll
      for (int mi = 0; mi < 4; ++mi) {
        const int row = wr * 64 + mi * 16 + l16;
        af[mi] = *(const bf16x8*)&As[row * BK + ((((ks << 2) + quad) ^ (l16 & 7)) << 3)];
      }
      #pragma unroll
      for (int ni = 0; ni < 4; ++ni) {
        const int row = wc * 64 + ni * 16 + l16;
        bfr[ni] = *(const bf16x8*)&Bs[row * BK + ((((ks << 2) + quad) ^ (l16 & 7)) << 3)];
      }
      #pragma unroll
      for (int mi = 0; mi < 4; ++mi)
        #pragma unroll
        for (int ni = 0; ni < 4; ++ni)
          acc[mi][ni] = __builtin_amdgcn_mfma_f32_16x16x32_bf16(af[mi], bfr[ni], acc[mi][ni], 0, 0, 0);
    }
    __syncthreads();
  }

  // C lane mapping: row = quad*4 + r, col = l16 (per 16x16 tile)
  const int mbase = m0 + wr * 64 + quad * 4;
  const int nbase = n0 + wc * 64 + l16;

  if constexpr (MODE == 0) {
    const int g = n0 >> 10;                  // 0=Q, 1=K, 2=V (block-uniform)
    u16* Qb = (u16*)Cv;
    if (g < 2) {
      u16* Cb = Qb + (size_t)g * 8388608ULL;
      const float* bp = (g == 0) ? b0 : b1;
      #pragma unroll
      for (int ni = 0; ni < 4; ++ni) {
        const int col = (nbase + ni * 16) & 1023;
        const float bv = bp[col];
        #pragma unroll
        for (int mi = 0; mi < 4; ++mi) {
          const size_t base = (size_t)(mbase + mi * 16) * 1024 + col;
          #pragma unroll
          for (int r = 0; r < 4; ++r)
            Cb[base + (size_t)r * 1024] = f2bf(acc[mi][ni][r] + bv);
        }
      }
    } else {
      u16* Vt = Qb + 16777216ULL;            // [4][1024][2048]
      #pragma unroll
      for (int ni = 0; ni < 4; ++ni) {
        const int col = (nbase + ni * 16) & 1023;
        const float bv = b2[col];
        #pragma unroll
        for (int mi = 0; mi < 4; ++mi) {
          const int row = mbase + mi * 16;
          u16x4 o;
          #pragma unroll
          for (int r = 0; r < 4; ++r) o[r] = f2bf(acc[mi][ni][r] + bv);
          const size_t idx = ((size_t)((row >> 11) * 1024 + col)) * 2048 + (row & 2047);
          *(u16x4*)&Vt[idx] = o;
        }
      }
    }
  } else if constexpr (MODE == 2) {
    u16* Cb = (u16*)Cv + z * sC;
    #pragma unroll
    for (int ni = 0; ni < 4; ++ni) {
      const int col = nbase + ni * 16;
      #pragma unroll
      for (int mi = 0; mi < 4; ++mi) {
        const size_t base = (size_t)(mbase + mi * 16) * ldc + col;
        #pragma unroll
        for (int r = 0; r < 4; ++r)
          Cb[base + (size_t)r * ldc] = f2bf(acc[mi][ni][r] * alpha);
      }
    }
  } else {
    float* Cf = (float*)Cv + z * sC;
    #pragma unroll
    for (int ni = 0; ni < 4; ++ni) {
      const int col = nbase + ni * 16;
      #pragma unroll
      for (int mi = 0; mi < 4; ++mi) {
        const size_t base = (size_t)(mbase + mi * 16) * ldc + col;
        #pragma unroll
        for (int r = 0; r < 4; ++r)
          Cf[base + (size_t)r * ldc] = acc[mi][ni][r];
      }
    }
  }
}

// one block per row; reads bf16 logits, writes fp32 attn to d_out and
// bf16 attn in-place (input to the PV gemm).
__global__ __launch_bounds__(256)
void softmax_rows(u16* __restrict__ logits, float* __restrict__ attn) {
  const int row = blockIdx.x;
  const int tid = threadIdx.x;
  u16*   lp = logits + (size_t)row * 2048 + tid * 8;
  float* ap = attn   + (size_t)row * 2048 + tid * 8;

  u16x8 raw = *(const u16x8*)lp;
  float v[8];
  #pragma unroll
  for (int j = 0; j < 8; ++j) v[j] = bf2f(raw[j]);

  float mx = v[0];
  #pragma unroll
  for (int j = 1; j < 8; ++j) mx = fmaxf(mx, v[j]);
  #pragma unroll
  for (int o = 32; o > 0; o >>= 1) mx = fmaxf(mx, __shfl_xor(mx, o, 64));

  __shared__ float smax[4], ssum[4];
  const int wv = tid >> 6, ln = tid & 63;
  if (ln == 0) smax[wv] = mx;
  __syncthreads();
  mx = fmaxf(fmaxf(smax[0], smax[1]), fmaxf(smax[2], smax[3]));

  float s = 0.f;
  #pragma unroll
  for (int j = 0; j < 8; ++j) { v[j] = __expf(v[j] - mx); s += v[j]; }
  #pragma unroll
  for (int o = 32; o > 0; o >>= 1) s += __shfl_xor(s, o, 64);
  if (ln == 0) ssum[wv] = s;
  __syncthreads();
  s = (ssum[0] + ssum[1]) + (ssum[2] + ssum[3]);
  const float inv = 1.f / s;

  u16x8 ob;
  #pragma unroll
  for (int j = 0; j < 8; ++j) { v[j] *= inv; ob[j] = f2bf(v[j]); }
  float4* apv = (float4*)ap;
  apv[0] = make_float4(v[0], v[1], v[2], v[3]);
  apv[1] = make_float4(v[4], v[5], v[6], v[7]);
  *(u16x8*)lp = ob;
}

extern "C" void kernel_launch(void* const* d_in, const int* in_sizes, int n_in,
                              void* d_out, int out_size, void* d_ws, size_t ws_size,
                              hipStream_t stream) {
  (void)in_sizes; (void)n_in; (void)out_size; (void)ws_size;
  const float* x    = (const float*)d_in[0];
  const float* wq_w = (const float*)d_in[1];
  const float* wq_b = (const float*)d_in[2];
  const float* wk_w = (const float*)d_in[3];
  const float* wk_b = (const float*)d_in[4];
  const float* wv_w = (const float*)d_in[5];
  const float* wv_b = (const float*)d_in[6];

  float* attn = (float*)d_out;                 // [4,2048,2048] fp32
  float* outp = attn + 16777216ULL;            // [4,2048,1024] fp32

  // ws layout (u16 elems): x_bf(8M) | wcat(3M) | Q(8M) | K(8M) | V^T(8M) | logits(16M)
  u16* xb   = (u16*)d_ws;
  u16* wcat = xb   + 8388608ULL;
  u16* Qb   = wcat + 3145728ULL;   // [8192][1024]
  u16* Kb   = Qb   + 8388608ULL;   // [8192][1024]
  u16* Vt   = Kb   + 8388608ULL;   // [4][1024][2048]
  u16* Lg   = Vt   + 8388608ULL;   // [4][2048][2048]

  cvt_f32_bf16<<<8192, 256, 0, stream>>>(x, xb);
  cvt_w3<<<3072, 256, 0, stream>>>(wq_w, wk_w, wv_w, wcat);

  // fused QKV: M=8192, N=3072, K=1024
  gemm_bt<0><<<1536, 256, 0, stream>>>(xb, wcat, Qb, wq_b, wk_b, wv_b,
                                       1024, 1024, 1024, 1024, 1.f, 0, 0, 0, 24, 64);

  // logits = Q K^T / 32 per batch: M=N=2048, K=1024
  gemm_bt<2><<<1024, 256, 0, stream>>>(Qb, Kb, Lg, nullptr, nullptr, nullptr,
                                       1024, 1024, 2048, 1024, 0.03125f,
                                       2097152ULL, 2097152ULL, 4194304ULL, 16, 16);

  softmax_rows<<<8192, 256, 0, stream>>>(Lg, attn);

  // out = attn V: M=2048, N=1024, K=2048 per batch
  gemm_bt<3><<<512, 256, 0, stream>>>(Lg, Vt, outp, nullptr, nullptr, nullptr,
                                      2048, 2048, 1024, 2048, 1.f,
                                      4194304ULL, 2097152ULL, 2097152ULL, 8, 16);
}

// Round 5
// 305.314 us; speedup vs baseline: 1.2258x; 1.0124x over previous
//
#include <hip/hip_runtime.h>

typedef unsigned short u16;
typedef u16 u16x4 __attribute__((ext_vector_type(4)));
typedef u16 u16x8 __attribute__((ext_vector_type(8)));
typedef __bf16 bf16x8 __attribute__((ext_vector_type(8)));
typedef float f32x16 __attribute__((ext_vector_type(16)));

static __device__ __forceinline__ u16 f2bf(float f) {
  unsigned u = __builtin_bit_cast(unsigned, f);
  u += 0x7fffu + ((u >> 16) & 1u);   // RNE; finite inputs
  return (u16)(u >> 16);
}
static __device__ __forceinline__ float bf2f(u16 h) {
  return __builtin_bit_cast(float, ((unsigned)h) << 16);
}

// async global->LDS, 16B/lane. LDS dest = wave-uniform base + lane*16.
static __device__ __forceinline__ void gload_lds16(const u16* g, u16* l) {
  u16* gn = const_cast<u16*>(g);
  __builtin_amdgcn_global_load_lds(
      (__attribute__((address_space(1))) unsigned int*)gn,
      (__attribute__((address_space(3))) unsigned int*)l,
      16, 0, 0);
}

__global__ __launch_bounds__(256)
void cvt_f32_bf16(const float* __restrict__ in, u16* __restrict__ out) {
  const int i = blockIdx.x * 256 + threadIdx.x;
  float4 f = ((const float4*)in)[i];
  u16x4 o = { f2bf(f.x), f2bf(f.y), f2bf(f.z), f2bf(f.w) };
  ((u16x4*)out)[i] = o;
}

__global__ __launch_bounds__(256)
void cvt_w3(const float* __restrict__ a, const float* __restrict__ b,
            const float* __restrict__ c, u16* __restrict__ out) {
  const int blk = blockIdx.x;       // 0..3071
  const int w = blk >> 10;
  const float* src = (w == 0) ? a : (w == 1) ? b : c;
  const int i = (blk & 1023) * 256 + threadIdx.x;
  float4 f = ((const float4*)src)[i];
  u16x4 o = { f2bf(f.x), f2bf(f.y), f2bf(f.z), f2bf(f.w) };
  ((u16x4*)(out + (size_t)w * 1048576ULL))[i] = o;
}

// C[m][n] = sum_k A[m][k]*B[n][k], k-contiguous. BM=BN=128, BK=64.
// mfma_f32_32x32x16_bf16; wave tile 64x64 = 2x2 of 32x32.
// A/B frag: [row=lane&31][k = kstep*16 + (lane>>5)*8 + j]
// C/D frag (m74/m101): col=lane&31, row=(reg&3)+8*(reg>>2)+4*(lane>>5)
// LDS XOR swizzle: LDS(row,c) holds global chunk c^(row&7) (16B chunks).
// MODE 0: fused QKV epilogue; Q scaled by 1/32 (folded logit scale).
// MODE 2: bf16 out, row-major ldc, z-strided   (logits, pre-scaled Q)
// MODE 3: fp32 out, row-major ldc, z-strided   (attn @ V^T)
template<int MODE>
__global__ __launch_bounds__(256)
void gemm_bt(const u16* __restrict__ Ain, const u16* __restrict__ Bin,
             void* __restrict__ Cv,
             const float* __restrict__ b0, const float* __restrict__ b1,
             const float* __restrict__ b2,
             int lda, int ldb, int ldc, int K,
             unsigned long long sA, unsigned long long sB, unsigned long long sC,
             int nbx, int nby)
{
  constexpr int BM = 128, BN = 128, BK = 64;
  __shared__ alignas(16) u16 As[BM * BK];
  __shared__ alignas(16) u16 Bs[BN * BK];

  // XCD-chunk + group-m swizzle
  const int nbxy = nbx * nby;
  const int bid  = blockIdx.x;
  const int flat = (bid & 7) * ((int)gridDim.x >> 3) + (bid >> 3);
  const int z    = flat / nbxy;
  const int rr   = flat - z * nbxy;
  const int width = nbx << 3;
  const int gid  = rr / width;
  const int rw   = rr - gid * width;
  const int by   = (gid << 3) + (rw & 7);
  const int bx   = rw >> 3;

  const u16* A = Ain + z * sA;
  const u16* B = Bin + z * sB;

  const int tid  = threadIdx.x;
  const int wave = tid >> 6;
  const int lane = tid & 63;
  const int l32  = lane & 31;
  const int half = lane >> 5;
  const int wr   = wave >> 1;     // 2x2 wave grid, 64x64 per wave
  const int wc   = wave & 1;

  const int m0 = by * BM;
  const int n0 = bx * BN;

  // staging: 64 lanes cover 8 rows x 8 chunks(16B) per instruction
  const int lr = lane >> 3;
  const int sc = ((lane & 7) ^ lr) * 8;     // swizzled global chunk
  const u16* Ag = A + (size_t)(m0 + wave * 32 + lr) * lda + sc;
  const u16* Bg = B + (size_t)(n0 + wave * 32 + lr) * ldb + sc;
  u16* Asb = &As[(wave * 32) * BK];
  u16* Bsb = &Bs[(wave * 32) * BK];

  f32x16 acc[2][2];
  #pragma unroll
  for (int i = 0; i < 2; ++i)
    #pragma unroll
    for (int j = 0; j < 2; ++j)
      #pragma unroll
      for (int r = 0; r < 16; ++r)
        acc[i][j][r] = 0.f;

  for (int k0 = 0; k0 < K; k0 += BK) {
    gload_lds16(Ag + k0,                    Asb);
    gload_lds16(Ag + (size_t) 8 * lda + k0, Asb +  8 * BK);
    gload_lds16(Ag + (size_t)16 * lda + k0, Asb + 16 * BK);
    gload_lds16(Ag + (size_t)24 * lda + k0, Asb + 24 * BK);
    gload_lds16(Bg + k0,                    Bsb);
    gload_lds16(Bg + (size_t) 8 * ldb + k0, Bsb +  8 * BK);
    gload_lds16(Bg + (size_t)16 * ldb + k0, Bsb + 16 * BK);
    gload_lds16(Bg + (size_t)24 * ldb + k0, Bsb + 24 * BK);
    __syncthreads();

    #pragma unroll
    for (int ks = 0; ks < 4; ++ks) {
      bf16x8 af[2], bfr[2];
      #pragma unroll
      for (int ti = 0; ti < 2; ++ti) {
        const int row = wr * 64 + ti * 32 + l32;
        const int ch  = ((ks * 2 + half) ^ (row & 7)) * 8;
        af[ti] = *(const bf16x8*)&As[row * BK + ch];
      }
      #pragma unroll
      for (int tj = 0; tj < 2; ++tj) {
        const int row = wc * 64 + tj * 32 + l32;
        const int ch  = ((ks * 2 + half) ^ (row & 7)) * 8;
        bfr[tj] = *(const bf16x8*)&Bs[row * BK + ch];
      }
      #pragma unroll
      for (int ti = 0; ti < 2; ++ti)
        #pragma unroll
        for (int tj = 0; tj < 2; ++tj)
          acc[ti][tj] = __builtin_amdgcn_mfma_f32_32x32x16_bf16(af[ti], bfr[tj], acc[ti][tj], 0, 0, 0);
    }
    __syncthreads();
  }

  // epilogue lane mapping
  const int colb = n0 + wc * 64 + l32;          // + tj*32
  const int rowb = m0 + wr * 64 + 4 * half;     // + ti*32 + (reg&3) + 8*(reg>>2)

  if constexpr (MODE == 0) {
    const int g = n0 >> 10;                     // 0=Q, 1=K, 2=V (block-uniform)
    u16* Qb = (u16*)Cv;
    if (g < 2) {
      u16* Cb = Qb + (size_t)g * 8388608ULL;
      const float* bp = (g == 0) ? b0 : b1;
      const float qs = (g == 0) ? 0.03125f : 1.0f;   // fold 1/sqrt(1024) into Q
      #pragma unroll
      for (int tj = 0; tj < 2; ++tj) {
        const int col = (colb + tj * 32) & 1023;
        const float bv = bp[col];
        #pragma unroll
        for (int ti = 0; ti < 2; ++ti)
          #pragma unroll
          for (int g4 = 0; g4 < 4; ++g4)
            #pragma unroll
            for (int r = 0; r < 4; ++r) {
              const int row = rowb + ti * 32 + g4 * 8 + r;
              Cb[(size_t)row * 1024 + col] = f2bf((acc[ti][tj][g4 * 4 + r] + bv) * qs);
            }
      }
    } else {
      u16* Vt = Qb + 16777216ULL;               // [4][1024][2048]
      #pragma unroll
      for (int tj = 0; tj < 2; ++tj) {
        const int col = (colb + tj * 32) & 1023;
        const float bv = b2[col];
        #pragma unroll
        for (int ti = 0; ti < 2; ++ti)
          #pragma unroll
          for (int g4 = 0; g4 < 4; ++g4) {
            const int row = rowb + ti * 32 + g4 * 8;   // 4 consecutive s
            u16x4 o;
            #pragma unroll
            for (int r = 0; r < 4; ++r) o[r] = f2bf(acc[ti][tj][g4 * 4 + r] + bv);
            const size_t idx = ((size_t)((row >> 11) * 1024 + col)) * 2048 + (row & 2047);
            *(u16x4*)&Vt[idx] = o;
          }
      }
    }
  } else if constexpr (MODE == 2) {
    u16* Cb = (u16*)Cv + z * sC;
    #pragma unroll
    for (int tj = 0; tj < 2; ++tj) {
      const int col = colb + tj * 32;
      #pragma unroll
      for (int ti = 0; ti < 2; ++ti)
        #pragma unroll
        for (int g4 = 0; g4 < 4; ++g4)
          #pragma unroll
          for (int r = 0; r < 4; ++r) {
            const int row = rowb + ti * 32 + g4 * 8 + r;
            Cb[(size_t)row * ldc + col] = f2bf(acc[ti][tj][g4 * 4 + r]);
          }
    }
  } else {
    float* Cf = (float*)Cv + z * sC;
    #pragma unroll
    for (int tj = 0; tj < 2; ++tj) {
      const int col = colb + tj * 32;
      #pragma unroll
      for (int ti = 0; ti < 2; ++ti)
        #pragma unroll
        for (int g4 = 0; g4 < 4; ++g4)
          #pragma unroll
          for (int r = 0; r < 4; ++r) {
            const int row = rowb + ti * 32 + g4 * 8 + r;
            Cf[(size_t)row * ldc + col] = acc[ti][tj][g4 * 4 + r];
          }
    }
  }
}

// one block per row; reads bf16 logits, writes fp32 attn to d_out and
// bf16 attn in-place (input to the PV gemm).
__global__ __launch_bounds__(256)
void softmax_rows(u16* __restrict__ logits, float* __restrict__ attn) {
  const int row = blockIdx.x;
  const int tid = threadIdx.x;
  u16*   lp = logits + (size_t)row * 2048 + tid * 8;
  float* ap = attn   + (size_t)row * 2048 + tid * 8;

  u16x8 raw = *(const u16x8*)lp;
  float v[8];
  #pragma unroll
  for (int j = 0; j < 8; ++j) v[j] = bf2f(raw[j]);

  float mx = v[0];
  #pragma unroll
  for (int j = 1; j < 8; ++j) mx = fmaxf(mx, v[j]);
  #pragma unroll
  for (int o = 32; o > 0; o >>= 1) mx = fmaxf(mx, __shfl_xor(mx, o, 64));

  __shared__ float smax[4], ssum[4];
  const int wv = tid >> 6, ln = tid & 63;
  if (ln == 0) smax[wv] = mx;
  __syncthreads();
  mx = fmaxf(fmaxf(smax[0], smax[1]), fmaxf(smax[2], smax[3]));

  float s = 0.f;
  #pragma unroll
  for (int j = 0; j < 8; ++j) { v[j] = __expf(v[j] - mx); s += v[j]; }
  #pragma unroll
  for (int o = 32; o > 0; o >>= 1) s += __shfl_xor(s, o, 64);
  if (ln == 0) ssum[wv] = s;
  __syncthreads();
  s = (ssum[0] + ssum[1]) + (ssum[2] + ssum[3]);
  const float inv = 1.f / s;

  u16x8 ob;
  #pragma unroll
  for (int j = 0; j < 8; ++j) { v[j] *= inv; ob[j] = f2bf(v[j]); }
  float4* apv = (float4*)ap;
  apv[0] = make_float4(v[0], v[1], v[2], v[3]);
  apv[1] = make_float4(v[4], v[5], v[6], v[7]);
  *(u16x8*)lp = ob;
}

extern "C" void kernel_launch(void* const* d_in, const int* in_sizes, int n_in,
                              void* d_out, int out_size, void* d_ws, size_t ws_size,
                              hipStream_t stream) {
  (void)in_sizes; (void)n_in; (void)out_size; (void)ws_size;
  const float* x    = (const float*)d_in[0];
  const float* wq_w = (const float*)d_in[1];
  const float* wq_b = (const float*)d_in[2];
  const float* wk_w = (const float*)d_in[3];
  const float* wk_b = (const float*)d_in[4];
  const float* wv_w = (const float*)d_in[5];
  const float* wv_b = (const float*)d_in[6];

  float* attn = (float*)d_out;                 // [4,2048,2048] fp32
  float* outp = attn + 16777216ULL;            // [4,2048,1024] fp32

  // ws layout (u16 elems): x_bf(8M) | wcat(3M) | Q(8M) | K(8M) | V^T(8M) | logits(16M)
  u16* xb   = (u16*)d_ws;
  u16* wcat = xb   + 8388608ULL;
  u16* Qb   = wcat + 3145728ULL;   // [8192][1024], pre-scaled by 1/32
  u16* Kb   = Qb   + 8388608ULL;   // [8192][1024]
  u16* Vt   = Kb   + 8388608ULL;   // [4][1024][2048]
  u16* Lg   = Vt   + 8388608ULL;   // [4][2048][2048]

  cvt_f32_bf16<<<8192, 256, 0, stream>>>(x, xb);
  cvt_w3<<<3072, 256, 0, stream>>>(wq_w, wk_w, wv_w, wcat);

  // fused QKV: M=8192, N=3072, K=1024
  gemm_bt<0><<<1536, 256, 0, stream>>>(xb, wcat, Qb, wq_b, wk_b, wv_b,
                                       1024, 1024, 1024, 1024, 0, 0, 0, 24, 64);

  // logits = (Q/32) K^T per batch: M=N=2048, K=1024
  gemm_bt<2><<<1024, 256, 0, stream>>>(Qb, Kb, Lg, nullptr, nullptr, nullptr,
                                       1024, 1024, 2048, 1024,
                                       2097152ULL, 2097152ULL, 4194304ULL, 16, 16);

  softmax_rows<<<8192, 256, 0, stream>>>(Lg, attn);

  // out = attn V: M=2048, N=1024, K=2048 per batch
  gemm_bt<3><<<512, 256, 0, stream>>>(Lg, Vt, outp, nullptr, nullptr, nullptr,
                                      2048, 2048, 1024, 2048,
                                      4194304ULL, 2097152ULL, 2097152ULL, 8, 16);
}